// Round 1
// baseline (378.856 us; speedup 1.0000x reference)
//
#include <hip/hip_runtime.h>
#include <hip/hip_bf16.h>
#include <cstdint>

#define HASH_SIZE (1u<<19)
#define NPTS 262144
#define DENS_N 2097152

typedef unsigned short u16;
typedef u16 u16x8 __attribute__((ext_vector_type(8)));
typedef __bf16 bf16x8 __attribute__((ext_vector_type(8)));
typedef float f32x4 __attribute__((ext_vector_type(4)));

__device__ __forceinline__ u16 f2bf(float f){
  uint32_t u = __builtin_bit_cast(uint32_t, f);
  u += 0x7fffu + ((u>>16)&1u);       // RNE; inputs are finite
  return (u16)(u>>16);
}
__device__ __forceinline__ float bf2f(u16 s){
  uint32_t u = ((uint32_t)s)<<16;
  return __builtin_bit_cast(float, u);
}

// W1 [512][64] f32 -> W1T [64][512] bf16 ; W2 [64][64] f32 -> W2T [64][64] bf16
__global__ void prep_weights(const float* __restrict__ W1, const float* __restrict__ W2,
                             u16* __restrict__ W1T, u16* __restrict__ W2T){
  int t = blockIdx.x*blockDim.x + threadIdx.x;
  int stride = gridDim.x*blockDim.x;
  for (int i=t; i<64*512; i+=stride){ int o=i>>9, k=i&511; W1T[i] = f2bf(W1[k*64+o]); }
  for (int i=t; i<64*64;  i+=stride){ int o=i>>6, k=i&63;  W2T[i] = f2bf(W2[k*64+o]); }
}

__global__ void density_sigmoid(const float4* __restrict__ in, float4* __restrict__ out){
  int i = blockIdx.x*blockDim.x + threadIdx.x;   // exactly 524288 threads
  float4 v = in[i];
  v.x = 1.f/(1.f+__expf(-v.x));
  v.y = 1.f/(1.f+__expf(-v.y));
  v.z = 1.f/(1.f+__expf(-v.z));
  v.w = 1.f/(1.f+__expf(-v.w));
  out[i] = v;
}

// One block = 256 threads = 4 waves, processes 16 points.
// GEMM1: [16 pts x 512] @ [512 x 64], K-chunk 32 == one hash level.
__global__ void __launch_bounds__(256) fused_mlp(
    const float* __restrict__ xyz, const float* __restrict__ fg,
    const u16* __restrict__ W1T, const u16* __restrict__ W2T,
    const float* __restrict__ b1, const float* __restrict__ b2,
    const float* __restrict__ W3, const float* __restrict__ b3,
    float* __restrict__ color)
{
  __shared__ uint32_t h_lds[16][17];
  __shared__ u16 h1_lds[16*64];
  __shared__ u16 h2_lds[16*64];

  const int t = threadIdx.x;
  const int pbase = blockIdx.x << 4;

  // phase 0: hashes for 16 points x 16 levels (must be bit-identical to jax:
  // f32 mul, trunc->u32, u32 wraparound hash)
  {
    const int p = t >> 4, s = t & 15;
    const float x = xyz[(pbase+p)*3+0];
    const float y = xyz[(pbase+p)*3+1];
    const float z = xyz[(pbase+p)*3+2];
    const float resf = (float)(16 << s);
    uint32_t ix = (uint32_t)(x*resf);
    uint32_t iy = (uint32_t)(y*resf);
    uint32_t iz = (uint32_t)(z*resf);
    h_lds[p][s] = (ix ^ (iy*2654435761u) ^ (iz*805459861u)) & (HASH_SIZE-1u);
  }
  __syncthreads();

  const int lane = t & 63;
  const int wave = t >> 6;
  const int arow = lane & 15;           // A row (point) and B col (within wave tile)
  const int kg   = lane >> 4;           // k-subgroup 0..3 (8 contiguous k each)
  const int ocol = (lane & 15) + (wave << 4);   // h1 output column 0..63

  // ---- GEMM1: features @ W1 ----
  f32x4 acc = {0.f,0.f,0.f,0.f};
  #pragma unroll
  for (int s=0; s<16; ++s){
    uint32_t h = h_lds[arow][s];
    const float* ap = fg + (size_t)((((uint32_t)s<<19) | h) * 32u) + kg*8;
    float4 a0 = *(const float4*)ap;
    float4 a1 = *(const float4*)(ap+4);
    u16x8 au;
    au[0]=f2bf(a0.x); au[1]=f2bf(a0.y); au[2]=f2bf(a0.z); au[3]=f2bf(a0.w);
    au[4]=f2bf(a1.x); au[5]=f2bf(a1.y); au[6]=f2bf(a1.z); au[7]=f2bf(a1.w);
    u16x8 bu = *(const u16x8*)(W1T + ((size_t)ocol<<9) + (s<<5) + (kg<<3));
    acc = __builtin_amdgcn_mfma_f32_16x16x32_bf16(
        __builtin_bit_cast(bf16x8, au), __builtin_bit_cast(bf16x8, bu), acc, 0,0,0);
  }
  {
    const float bias = b1[ocol];
    #pragma unroll
    for (int r=0; r<4; ++r){
      const int prow = (kg<<2) + r;        // C row = point
      float v = acc[r] + bias;
      v = v > 0.f ? v : 0.f;
      h1_lds[(prow*64 + ocol) ^ ((prow&7)<<3)] = f2bf(v);  // XOR-swizzled
    }
  }
  __syncthreads();

  // ---- GEMM2: h1 @ W2 ----
  f32x4 acc2 = {0.f,0.f,0.f,0.f};
  #pragma unroll
  for (int kc=0; kc<2; ++kc){
    const int aidx = (arow*64 + kc*32 + kg*8) ^ ((arow&7)<<3);
    u16x8 au = *(const u16x8*)(&h1_lds[aidx]);
    u16x8 bu = *(const u16x8*)(W2T + (ocol<<6) + (kc<<5) + (kg<<3));
    acc2 = __builtin_amdgcn_mfma_f32_16x16x32_bf16(
        __builtin_bit_cast(bf16x8, au), __builtin_bit_cast(bf16x8, bu), acc2, 0,0,0);
  }
  {
    const float bias = b2[ocol];
    #pragma unroll
    for (int r=0; r<4; ++r){
      const int prow = (kg<<2) + r;
      float v = acc2[r] + bias;
      v = v > 0.f ? v : 0.f;
      h2_lds[(prow*64 + ocol) ^ ((prow&7)<<3)] = f2bf(v);
    }
  }
  __syncthreads();

  // ---- layer 3: [16 x 64] @ [64 x 3] + sigmoid ----
  if (t < 48){
    const int p = t / 3, c = t % 3;
    float sum = b3[c];
    #pragma unroll
    for (int o=0; o<64; ++o){
      sum += bf2f(h2_lds[(p*64+o) ^ ((p&7)<<3)]) * W3[o*3+c];
    }
    color[(size_t)(pbase+p)*3 + c] = 1.f/(1.f+__expf(-sum));
  }
}

extern "C" void kernel_launch(void* const* d_in, const int* in_sizes, int n_in,
                              void* d_out, int out_size, void* d_ws, size_t ws_size,
                              hipStream_t stream){
  const float* xyz  = (const float*)d_in[0];
  const float* fg   = (const float*)d_in[1];
  const float* dens = (const float*)d_in[2];
  const float* W1   = (const float*)d_in[3];
  const float* b1   = (const float*)d_in[4];
  const float* W2   = (const float*)d_in[5];
  const float* b2   = (const float*)d_in[6];
  const float* W3   = (const float*)d_in[7];
  const float* b3   = (const float*)d_in[8];
  float* out = (float*)d_out;

  u16* W1T = (u16*)d_ws;            // 64*512*2 = 64 KiB
  u16* W2T = W1T + 64*512;          // 64*64*2  =  8 KiB

  hipLaunchKernelGGL(prep_weights, dim3(64), dim3(256), 0, stream, W1, W2, W1T, W2T);
  hipLaunchKernelGGL(density_sigmoid, dim3(DENS_N/1024), dim3(256), 0, stream,
                     (const float4*)dens, (float4*)out);
  hipLaunchKernelGGL(fused_mlp, dim3(NPTS/16), dim3(256), 0, stream,
                     xyz, fg, W1T, W2T, b1, b2, W3, b3, out + DENS_N);
}

// Round 2
// 216.764 us; speedup vs baseline: 1.7478x; 1.7478x over previous
//
#include <hip/hip_runtime.h>
#include <hip/hip_bf16.h>
#include <cstdint>

#define HASH_SIZE (1u<<19)
#define NPTS 262144
#define DENS_N 2097152

typedef unsigned short u16;
typedef u16 u16x8 __attribute__((ext_vector_type(8)));
typedef __bf16 bf16x8 __attribute__((ext_vector_type(8)));
typedef float f32x4 __attribute__((ext_vector_type(4)));

__device__ __forceinline__ u16 f2bf(float f){
  uint32_t u = __builtin_bit_cast(uint32_t, f);
  u += 0x7fffu + ((u>>16)&1u);       // RNE; inputs are finite
  return (u16)(u>>16);
}
__device__ __forceinline__ float bf2f(u16 s){
  uint32_t u = ((uint32_t)s)<<16;
  return __builtin_bit_cast(float, u);
}

// W1 [512][64] f32 -> W1T [64][512] bf16 ; W2 [64][64] f32 -> W2T [64][64] bf16
__global__ void prep_weights(const float* __restrict__ W1, const float* __restrict__ W2,
                             u16* __restrict__ W1T, u16* __restrict__ W2T){
  int t = blockIdx.x*blockDim.x + threadIdx.x;
  int stride = gridDim.x*blockDim.x;
  for (int i=t; i<64*512; i+=stride){ int o=i>>9, k=i&511; W1T[i] = f2bf(W1[k*64+o]); }
  for (int i=t; i<64*64;  i+=stride){ int o=i>>6, k=i&63;  W2T[i] = f2bf(W2[k*64+o]); }
}

__global__ void density_sigmoid(const float4* __restrict__ in, float4* __restrict__ out){
  int i = blockIdx.x*blockDim.x + threadIdx.x;   // exactly 524288 threads
  float4 v = in[i];
  v.x = 1.f/(1.f+__expf(-v.x));
  v.y = 1.f/(1.f+__expf(-v.y));
  v.z = 1.f/(1.f+__expf(-v.z));
  v.w = 1.f/(1.f+__expf(-v.w));
  out[i] = v;
}

// One block = 256 threads = 4 INDEPENDENT waves; each wave owns 16 points and
// computes ALL 64 MLP columns for them (no cross-wave redundant gathers, no
// __syncthreads). GEMM1: [16 x 512] @ [512 x 64]; K-chunk 32 == one hash level.
__global__ void __launch_bounds__(256) fused_mlp(
    const float* __restrict__ xyz, const float* __restrict__ fg,
    const u16* __restrict__ W1T, const u16* __restrict__ W2T,
    const float* __restrict__ b1, const float* __restrict__ b2,
    const float* __restrict__ W3, const float* __restrict__ b3,
    float* __restrict__ color)
{
  __shared__ u16 h1_lds[4][16*64];
  __shared__ u16 h2_lds[4][16*64];

  const int t = threadIdx.x;
  const int wave = t >> 6;
  const int lane = t & 63;
  const int p  = lane & 15;            // point within this wave's 16-point tile
  const int kg = lane >> 4;            // k-subgroup 0..3 (8 contiguous k each)
  const int gp = (blockIdx.x << 6) + (wave << 4) + p;   // global point id

  // hashes for this lane's point, all 16 levels, in registers
  // (bit-identical to jax: f32 mul, trunc->u32, u32 wraparound hash)
  const float x = xyz[gp*3+0];
  const float y = xyz[gp*3+1];
  const float z = xyz[gp*3+2];
  uint32_t h[16];
  #pragma unroll
  for (int s=0; s<16; ++s){
    const float resf = (float)(16 << s);
    uint32_t ix = (uint32_t)(x*resf);
    uint32_t iy = (uint32_t)(y*resf);
    uint32_t iz = (uint32_t)(z*resf);
    h[s] = (ix ^ (iy*2654435761u) ^ (iz*805459861u)) & (HASH_SIZE-1u);
  }

  // ---- GEMM1: features @ W1 -> h1 [16 x 64] ----
  f32x4 acc[4];
  #pragma unroll
  for (int tt=0; tt<4; ++tt) acc[tt] = (f32x4){0.f,0.f,0.f,0.f};

  #pragma unroll
  for (int s=0; s<16; ++s){
    const float* ap = fg + (size_t)((((uint32_t)s<<19) | h[s]) * 32u) + kg*8;
    float4 a0 = *(const float4*)ap;
    float4 a1 = *(const float4*)(ap+4);
    u16x8 au;
    au[0]=f2bf(a0.x); au[1]=f2bf(a0.y); au[2]=f2bf(a0.z); au[3]=f2bf(a0.w);
    au[4]=f2bf(a1.x); au[5]=f2bf(a1.y); au[6]=f2bf(a1.z); au[7]=f2bf(a1.w);
    bf16x8 ab = __builtin_bit_cast(bf16x8, au);
    #pragma unroll
    for (int tt=0; tt<4; ++tt){
      u16x8 bu = *(const u16x8*)(W1T + ((((lane&15)+(tt<<4))<<9) + (s<<5) + (kg<<3)));
      acc[tt] = __builtin_amdgcn_mfma_f32_16x16x32_bf16(
          ab, __builtin_bit_cast(bf16x8, bu), acc[tt], 0,0,0);
    }
  }
  #pragma unroll
  for (int tt=0; tt<4; ++tt){
    const int col = (lane&15) + (tt<<4);
    const float bias = b1[col];
    #pragma unroll
    for (int r=0; r<4; ++r){
      const int row = (kg<<2) + r;        // C row = point within tile
      float v = acc[tt][r] + bias;
      v = v > 0.f ? v : 0.f;
      h1_lds[wave][(row*64 + col) ^ ((row&7)<<3)] = f2bf(v);  // XOR-swizzled
    }
  }

  // ---- GEMM2: h1 @ W2 -> h2 [16 x 64] ----  (same-wave LDS dep; no barrier)
  f32x4 acc2[4];
  #pragma unroll
  for (int tt=0; tt<4; ++tt) acc2[tt] = (f32x4){0.f,0.f,0.f,0.f};

  #pragma unroll
  for (int kc=0; kc<2; ++kc){
    const int aidx = (p*64 + kc*32 + kg*8) ^ ((p&7)<<3);
    u16x8 au = *(const u16x8*)(&h1_lds[wave][aidx]);
    bf16x8 ab = __builtin_bit_cast(bf16x8, au);
    #pragma unroll
    for (int tt=0; tt<4; ++tt){
      u16x8 bu = *(const u16x8*)(W2T + ((((lane&15)+(tt<<4))<<6) + (kc<<5) + (kg<<3)));
      acc2[tt] = __builtin_amdgcn_mfma_f32_16x16x32_bf16(
          ab, __builtin_bit_cast(bf16x8, bu), acc2[tt], 0,0,0);
    }
  }
  #pragma unroll
  for (int tt=0; tt<4; ++tt){
    const int col = (lane&15) + (tt<<4);
    const float bias = b2[col];
    #pragma unroll
    for (int r=0; r<4; ++r){
      const int row = (kg<<2) + r;
      float v = acc2[tt][r] + bias;
      v = v > 0.f ? v : 0.f;
      h2_lds[wave][(row*64 + col) ^ ((row&7)<<3)] = f2bf(v);
    }
  }

  // ---- layer 3: [16 x 64] @ [64 x 3] + sigmoid ----
  if (lane < 48){
    const int pp = lane / 3, c = lane % 3;
    float sum = b3[c];
    #pragma unroll
    for (int o=0; o<64; ++o){
      sum += bf2f(h2_lds[wave][(pp*64+o) ^ ((pp&7)<<3)]) * W3[o*3+c];
    }
    const int gpp = (blockIdx.x << 6) + (wave << 4) + pp;
    color[(size_t)gpp*3 + c] = 1.f/(1.f+__expf(-sum));
  }
}

extern "C" void kernel_launch(void* const* d_in, const int* in_sizes, int n_in,
                              void* d_out, int out_size, void* d_ws, size_t ws_size,
                              hipStream_t stream){
  const float* xyz  = (const float*)d_in[0];
  const float* fg   = (const float*)d_in[1];
  const float* dens = (const float*)d_in[2];
  const float* W1   = (const float*)d_in[3];
  const float* b1   = (const float*)d_in[4];
  const float* W2   = (const float*)d_in[5];
  const float* b2   = (const float*)d_in[6];
  const float* W3   = (const float*)d_in[7];
  const float* b3   = (const float*)d_in[8];
  float* out = (float*)d_out;

  u16* W1T = (u16*)d_ws;            // 64*512*2 = 64 KiB
  u16* W2T = W1T + 64*512;          // 64*64*2  =  8 KiB

  hipLaunchKernelGGL(prep_weights, dim3(64), dim3(256), 0, stream, W1, W2, W1T, W2T);
  hipLaunchKernelGGL(density_sigmoid, dim3(DENS_N/1024), dim3(256), 0, stream,
                     (const float4*)dens, (float4*)out);
  hipLaunchKernelGGL(fused_mlp, dim3(NPTS/64), dim3(256), 0, stream,
                     xyz, fg, W1T, W2T, b1, b2, W3, b3, out + DENS_N);
}